// Round 3
// baseline (113.025 us; speedup 1.0000x reference)
//
#include <hip/hip_runtime.h>
#include <math.h>

// SpectralAngleLoss: B=8192 rows, N=256 peaks, 2000 bins.
//
// Identity: with p[b] the final histogram, dot = sum_i pin_i*q[pbin_i],
// p2 = sum_i pin_i*p[pbin_i], t2 = sum_j tin_j*q[tbin_j] -> scalar LDS
// reads per peak after the scatter; no 2000-bin scan.
//
// v4 = v3 row phase (bit-identical, absmax 0.0) + FUSED final reduction:
// last-block-done pattern (device-scope atomic counter in workspace,
// re-zeroed each replay by a 4-byte hipMemsetAsync). The last block runs a
// verbatim copy of the old sal_reduce_kernel body -> same summation order,
// bit-identical final scalar. Saves one kernel dispatch + graph gap.

#define SAL_NUM_BINS 2000
#define SAL_B 8192
#define SAL_N 256
#define SAL_GRID (SAL_B / 8)          // 1024 blocks x 4 waves x 2 rows

__global__ __launch_bounds__(256, 4) void sal_fused_kernel(
    const float* __restrict__ pred_mz,
    const float* __restrict__ pred_int,
    const float* __restrict__ targ_mz,
    const float* __restrict__ targ_int,
    const float* __restrict__ targ_mask,
    float* __restrict__ wave_partial,     // 4096 floats in workspace
    unsigned int* __restrict__ counter,   // 1 uint in workspace (memset to 0)
    float* __restrict__ out)
{
    __shared__ __align__(16) float hist[4][SAL_NUM_BINS];   // 32000 B
    __shared__ float pbuf[4];             // per-wave partials
    __shared__ float rbuf[4];             // reduce scratch (verbatim v3 reduce)
    __shared__ bool  amLast;
    const int t = threadIdx.x;
    const int w = t >> 6;                 // wave in block
    const int l = t & 63;                 // lane
    const int baseA = (blockIdx.x * 8 + w * 2) * SAL_N;

    // issue both rows' global loads first (10 x 16B/lane, coalesced)
    float4 pmz[2], pin[2], tmz[2], ti4[2], tm4[2];
    #pragma unroll
    for (int r = 0; r < 2; ++r) {
        const int base = baseA + r * SAL_N;
        pmz[r] = ((const float4*)(pred_mz   + base))[l];
        pin[r] = ((const float4*)(pred_int  + base))[l];
        tmz[r] = ((const float4*)(targ_mz   + base))[l];
        ti4[r] = ((const float4*)(targ_int  + base))[l];
        tm4[r] = ((const float4*)(targ_mask + base))[l];
    }

    // zero this wave's private 8 KB under the loads (500 float4 / 64 lanes).
    // Single wave owns the region -> in-order DS, no barrier needed.
    {
        float4* h4 = (float4*)&hist[w][0];
        const float4 z = make_float4(0.f, 0.f, 0.f, 0.f);
        #pragma unroll
        for (int i = 0; i < 8; ++i) {
            const int idx = l + i * 64;
            if (idx < SAL_NUM_BINS / 4) h4[idx] = z;
        }
    }

    float* __restrict__ h = &hist[w][0];
    float dotv[2], p2v[2], t2v[2];

    #pragma unroll
    for (int r = 0; r < 2; ++r) {
        const float4 tin = make_float4(ti4[r].x * tm4[r].x, ti4[r].y * tm4[r].y,
                                       ti4[r].z * tm4[r].z, ti4[r].w * tm4[r].w);
        const int pb0 = min(max((int)(pmz[r].x * 2000.0f), 0), SAL_NUM_BINS - 1);
        const int pb1 = min(max((int)(pmz[r].y * 2000.0f), 0), SAL_NUM_BINS - 1);
        const int pb2 = min(max((int)(pmz[r].z * 2000.0f), 0), SAL_NUM_BINS - 1);
        const int pb3 = min(max((int)(pmz[r].w * 2000.0f), 0), SAL_NUM_BINS - 1);
        const int tb0 = min(max((int)(tmz[r].x * 2000.0f), 0), SAL_NUM_BINS - 1);
        const int tb1 = min(max((int)(tmz[r].y * 2000.0f), 0), SAL_NUM_BINS - 1);
        const int tb2 = min(max((int)(tmz[r].z * 2000.0f), 0), SAL_NUM_BINS - 1);
        const int tb3 = min(max((int)(tmz[r].w * 2000.0f), 0), SAL_NUM_BINS - 1);

        // ---- phase Q: target histogram ----
        atomicAdd(&h[tb0], tin.x);         // ds_add_f32, wave-private
        atomicAdd(&h[tb1], tin.y);
        atomicAdd(&h[tb2], tin.z);
        atomicAdd(&h[tb3], tin.w);

        float dot = 0.f, p2 = 0.f, t2 = 0.f;
        dot = fmaf(pin[r].x, h[pb0], dot);   // q at pred bins (0 if untouched)
        dot = fmaf(pin[r].y, h[pb1], dot);
        dot = fmaf(pin[r].z, h[pb2], dot);
        dot = fmaf(pin[r].w, h[pb3], dot);
        t2  = fmaf(tin.x, h[tb0], t2);
        t2  = fmaf(tin.y, h[tb1], t2);
        t2  = fmaf(tin.z, h[tb2], t2);
        t2  = fmaf(tin.w, h[tb3], t2);

        // undo Q (in-order DS: the reads above complete first)
        h[tb0] = 0.0f; h[tb1] = 0.0f; h[tb2] = 0.0f; h[tb3] = 0.0f;

        // ---- phase P: pred histogram ----
        atomicAdd(&h[pb0], pin[r].x);
        atomicAdd(&h[pb1], pin[r].y);
        atomicAdd(&h[pb2], pin[r].z);
        atomicAdd(&h[pb3], pin[r].w);

        p2 = fmaf(pin[r].x, h[pb0], p2);
        p2 = fmaf(pin[r].y, h[pb1], p2);
        p2 = fmaf(pin[r].z, h[pb2], p2);
        p2 = fmaf(pin[r].w, h[pb3], p2);

        if (r < 1) {                        // undo P (not needed on last row)
            h[pb0] = 0.0f; h[pb1] = 0.0f; h[pb2] = 0.0f; h[pb3] = 0.0f;
        }

        dotv[r] = dot; p2v[r] = p2; t2v[r] = t2;
    }

    // batched reduces: 6 independent chains hide cross-lane latency.
    // Same __shfl_down butterfly as v1/v2/v3 -> bit-identical lane-0 sums.
    #pragma unroll
    for (int off = 32; off > 0; off >>= 1) {
        #pragma unroll
        for (int r = 0; r < 2; ++r) {
            dotv[r] += __shfl_down(dotv[r], off, 64);
            p2v[r]  += __shfl_down(p2v[r],  off, 64);
            t2v[r]  += __shfl_down(t2v[r],  off, 64);
        }
    }

    if (l == 0) {
        float s = 0.f;
        #pragma unroll
        for (int r = 0; r < 2; ++r) {
            const float pn = fmaxf(sqrtf(p2v[r]), 1e-8f);
            const float tn = fmaxf(sqrtf(t2v[r]), 1e-8f);
            float cs = dotv[r] / (pn * tn);
            cs = fminf(fmaxf(cs, -1.0f), 1.0f);
            s += acosf(cs) * (float)(1.0 / M_PI);
        }
        pbuf[w] = s;
    }
    __syncthreads();

    // ---- publish partials + last-block handoff (single-thread store+fence) ----
    if (t == 0) {
        ((float4*)wave_partial)[blockIdx.x] =            // layout: [bid*4 + w]
            make_float4(pbuf[0], pbuf[1], pbuf[2], pbuf[3]);
        __threadfence();                                  // release partials
        const unsigned int old = atomicAdd(counter, 1u);  // device scope
        amLast = (old == SAL_GRID - 1);
    }
    __syncthreads();
    if (!amLast) return;
    __threadfence();                                      // acquire partials

    // ---- verbatim v3 sal_reduce_kernel body (bit-identical sum order) ----
    const float4* wp4 = (const float4*)wave_partial;
    float s = 0.0f;
    #pragma unroll
    for (int i = 0; i < 4096 / 4 / 256; ++i) {   // 1024 float4
        float4 v = wp4[t + i * 256];
        s += (v.x + v.y) + (v.z + v.w);
    }
    #pragma unroll
    for (int off = 32; off > 0; off >>= 1) s += __shfl_down(s, off, 64);
    if ((t & 63) == 0) rbuf[t >> 6] = s;
    __syncthreads();
    if (t == 0) out[0] = ((rbuf[0] + rbuf[1]) + (rbuf[2] + rbuf[3])) * (float)(1.0 / SAL_B);
}

extern "C" void kernel_launch(void* const* d_in, const int* in_sizes, int n_in,
                              void* d_out, int out_size, void* d_ws, size_t ws_size,
                              hipStream_t stream) {
    const float* pred_mz   = (const float*)d_in[0];
    const float* pred_int  = (const float*)d_in[1];
    const float* targ_mz   = (const float*)d_in[2];
    const float* targ_int  = (const float*)d_in[3];
    const float* targ_mask = (const float*)d_in[4];
    float* wave_partial = (float*)d_ws;                       // 4096 floats
    unsigned int* counter = (unsigned int*)((char*)d_ws + 4096 * sizeof(float));
    float* out = (float*)d_out;

    hipMemsetAsync(counter, 0, sizeof(unsigned int), stream); // graph-safe stream op
    sal_fused_kernel<<<SAL_GRID, 256, 0, stream>>>(pred_mz, pred_int, targ_mz,
                                                   targ_int, targ_mask,
                                                   wave_partial, counter, out);
}

// Round 4
// 105.540 us; speedup vs baseline: 1.0709x; 1.0709x over previous
//
#include <hip/hip_runtime.h>
#include <math.h>

// SpectralAngleLoss: B=8192 rows, N=256 peaks, 2000 bins.
//
// Identity: with p[b] the final histogram, dot = sum_i pin_i*q[pbin_i],
// p2 = sum_i pin_i*p[pbin_i], t2 = sum_j tin_j*q[tbin_j] -> 3 scalar LDS
// reads per peak after the scatter; no 2000-bin scan.
//
// BARRIER-FREE wave-private histograms: each of the 4 waves in a block owns
// a [2][2000] LDS region (64 KB/block -> 2 blocks/CU, 8 waves/CU) and
// processes 2 rows sequentially: zero once, scatter/gather row A, scatter-
// undo (write 0 back to touched bins), then row B. All DS ops are wave-
// ordered (lockstep + lgkmcnt) -> zero __syncthreads. Wave writes the sum
// of its 2 angles; kernel 2 tree-reduces 4096 partials. Fully deterministic.
//
// Session ledger (measured): v0=105.0us, v2(1-wave blocks)=107.1,
// v3(8KB hist)=106.5, v4(fused reduce)=113.0. All occupancy/LDS/fusion
// levers move <=2us or regress: the timed window is ~86us of harness
// workspace poison-fill at the HBM roofline + ~12us of kernels near their
// memory floor. v0 is the best verified configuration -> keep it.

#define SAL_NUM_BINS 2000
#define SAL_B 8192
#define SAL_N 256

__device__ __forceinline__ float sal_row_angle(
    float* __restrict__ hp, float* __restrict__ hq,   // wave-private hists
    const float4& pmz, const float4& pin,
    const float4& tmz, const float4& tin,
    bool undo)
{
    const int pb0 = min(max((int)(pmz.x * 2000.0f), 0), SAL_NUM_BINS - 1);
    const int pb1 = min(max((int)(pmz.y * 2000.0f), 0), SAL_NUM_BINS - 1);
    const int pb2 = min(max((int)(pmz.z * 2000.0f), 0), SAL_NUM_BINS - 1);
    const int pb3 = min(max((int)(pmz.w * 2000.0f), 0), SAL_NUM_BINS - 1);
    const int tb0 = min(max((int)(tmz.x * 2000.0f), 0), SAL_NUM_BINS - 1);
    const int tb1 = min(max((int)(tmz.y * 2000.0f), 0), SAL_NUM_BINS - 1);
    const int tb2 = min(max((int)(tmz.z * 2000.0f), 0), SAL_NUM_BINS - 1);
    const int tb3 = min(max((int)(tmz.w * 2000.0f), 0), SAL_NUM_BINS - 1);

    atomicAdd(&hp[pb0], pin.x);   // ds_add_f32, wave-private region
    atomicAdd(&hp[pb1], pin.y);
    atomicAdd(&hp[pb2], pin.z);
    atomicAdd(&hp[pb3], pin.w);
    atomicAdd(&hq[tb0], tin.x);
    atomicAdd(&hq[tb1], tin.y);
    atomicAdd(&hq[tb2], tin.z);
    atomicAdd(&hq[tb3], tin.w);
    // compiler orders dependent ds_reads after the atomics via lgkmcnt

    float dot = 0.f, p2 = 0.f, t2 = 0.f;
    dot = fmaf(pin.x, hq[pb0], dot);  p2 = fmaf(pin.x, hp[pb0], p2);
    dot = fmaf(pin.y, hq[pb1], dot);  p2 = fmaf(pin.y, hp[pb1], p2);
    dot = fmaf(pin.z, hq[pb2], dot);  p2 = fmaf(pin.z, hp[pb2], p2);
    dot = fmaf(pin.w, hq[pb3], dot);  p2 = fmaf(pin.w, hp[pb3], p2);
    t2  = fmaf(tin.x, hq[tb0], t2);
    t2  = fmaf(tin.y, hq[tb1], t2);
    t2  = fmaf(tin.z, hq[tb2], t2);
    t2  = fmaf(tin.w, hq[tb3], t2);

    if (undo) {                       // in-order DS: reads above complete first
        hp[pb0] = 0.0f; hp[pb1] = 0.0f; hp[pb2] = 0.0f; hp[pb3] = 0.0f;
        hq[tb0] = 0.0f; hq[tb1] = 0.0f; hq[tb2] = 0.0f; hq[tb3] = 0.0f;
    }

    #pragma unroll
    for (int off = 32; off > 0; off >>= 1) {
        dot += __shfl_down(dot, off, 64);
        p2  += __shfl_down(p2,  off, 64);
        t2  += __shfl_down(t2,  off, 64);
    }
    float pn = fmaxf(sqrtf(p2), 1e-8f);
    float tn = fmaxf(sqrtf(t2), 1e-8f);
    float cs = dot / (pn * tn);
    cs = fminf(fmaxf(cs, -1.0f), 1.0f);
    return acosf(cs) * (float)(1.0 / M_PI);   // valid on lane 0
}

__global__ __launch_bounds__(256) void sal_row_kernel(
    const float* __restrict__ pred_mz,
    const float* __restrict__ pred_int,
    const float* __restrict__ targ_mz,
    const float* __restrict__ targ_int,
    const float* __restrict__ targ_mask,
    float* __restrict__ wave_partial)     // 4096 entries: sum of 2 angles
{
    __shared__ __align__(16) float hist[4][2][SAL_NUM_BINS];  // 64000 B
    const int t = threadIdx.x;
    const int w = t >> 6;                 // wave in block
    const int l = t & 63;                 // lane
    const int rowA = blockIdx.x * 8 + w * 2;     // two consecutive rows/wave
    const int baseA = rowA * SAL_N;
    const int baseB = baseA + SAL_N;

    // issue both rows' global loads first (10 x 16B/lane, coalesced)
    const float4 pmzA = ((const float4*)(pred_mz   + baseA))[l];
    const float4 pinA = ((const float4*)(pred_int  + baseA))[l];
    const float4 tmzA = ((const float4*)(targ_mz   + baseA))[l];
    const float4 ti4A = ((const float4*)(targ_int  + baseA))[l];
    const float4 tm4A = ((const float4*)(targ_mask + baseA))[l];
    const float4 pmzB = ((const float4*)(pred_mz   + baseB))[l];
    const float4 pinB = ((const float4*)(pred_int  + baseB))[l];
    const float4 tmzB = ((const float4*)(targ_mz   + baseB))[l];
    const float4 ti4B = ((const float4*)(targ_int  + baseB))[l];
    const float4 tm4B = ((const float4*)(targ_mask + baseB))[l];

    // zero this wave's private 16 KB under the loads: 1000 float4 / 64 lanes
    {
        float4* h4 = (float4*)&hist[w][0][0];
        const float4 z = make_float4(0.f, 0.f, 0.f, 0.f);
        #pragma unroll
        for (int i = 0; i < 16; ++i) {
            int idx = l + i * 64;
            if (idx < (2 * SAL_NUM_BINS) / 4) h4[idx] = z;
        }
    }

    float* hp = &hist[w][0][0];
    float* hq = &hist[w][1][0];

    const float4 tinA = make_float4(ti4A.x * tm4A.x, ti4A.y * tm4A.y,
                                    ti4A.z * tm4A.z, ti4A.w * tm4A.w);
    const float4 tinB = make_float4(ti4B.x * tm4B.x, ti4B.y * tm4B.y,
                                    ti4B.z * tm4B.z, ti4B.w * tm4B.w);

    const float angA = sal_row_angle(hp, hq, pmzA, pinA, tmzA, tinA, true);
    const float angB = sal_row_angle(hp, hq, pmzB, pinB, tmzB, tinB, false);

    if (l == 0) wave_partial[blockIdx.x * 4 + w] = angA + angB;
}

__global__ __launch_bounds__(256) void sal_reduce_kernel(
    const float* __restrict__ wave_partial, float* __restrict__ out)
{
    const int t = threadIdx.x;
    const float4* wp4 = (const float4*)wave_partial;
    float s = 0.0f;
    #pragma unroll
    for (int i = 0; i < 4096 / 4 / 256; ++i) {   // 1024 float4
        float4 v = wp4[t + i * 256];
        s += (v.x + v.y) + (v.z + v.w);
    }
    #pragma unroll
    for (int off = 32; off > 0; off >>= 1) s += __shfl_down(s, off, 64);
    __shared__ float rbuf[4];
    if ((t & 63) == 0) rbuf[t >> 6] = s;
    __syncthreads();
    if (t == 0) out[0] = ((rbuf[0] + rbuf[1]) + (rbuf[2] + rbuf[3])) * (float)(1.0 / SAL_B);
}

extern "C" void kernel_launch(void* const* d_in, const int* in_sizes, int n_in,
                              void* d_out, int out_size, void* d_ws, size_t ws_size,
                              hipStream_t stream) {
    const float* pred_mz   = (const float*)d_in[0];
    const float* pred_int  = (const float*)d_in[1];
    const float* targ_mz   = (const float*)d_in[2];
    const float* targ_int  = (const float*)d_in[3];
    const float* targ_mask = (const float*)d_in[4];
    float* wave_partial = (float*)d_ws;   // 4096 floats, fully overwritten
    float* out = (float*)d_out;

    sal_row_kernel<<<SAL_B / 8, 256, 0, stream>>>(pred_mz, pred_int, targ_mz,
                                                  targ_int, targ_mask, wave_partial);
    sal_reduce_kernel<<<1, 256, 0, stream>>>(wave_partial, out);
}